// Round 3
// baseline (271.017 us; speedup 1.0000x reference)
//
#include <hip/hip_runtime.h>

#define NB 256   // batch
#define NS 256   // seq len == number of steps
#define NE 2     // encoder dim
#define ND 128   // decoder dim
#define NT 512   // threads per block (8 waves)
#define NN 16    // Chebyshev nodes/degree for the h -> context map
#define SLOTH 160 // padded halfs per f16 ring slot (4 slices of 40)

typedef float vf4 __attribute__((ext_vector_type(4)));
typedef _Float16 f16x8 __attribute__((ext_vector_type(8)));
typedef float f32x4 __attribute__((ext_vector_type(4)));

constexpr float L2E = 1.4426950408889634f;  // log2(e)
constexpr float PI_F = 3.14159265358979323846f;

// Monomial coefficients of Chebyshev T_k: T_k(h) = sum_m CT[k][m] h^m (exact ints).
__device__ const float CT[16][16] = {
 {1,0,0,0,0,0,0,0,0,0,0,0,0,0,0,0},
 {0,1,0,0,0,0,0,0,0,0,0,0,0,0,0,0},
 {-1,0,2,0,0,0,0,0,0,0,0,0,0,0,0,0},
 {0,-3,0,4,0,0,0,0,0,0,0,0,0,0,0,0},
 {1,0,-8,0,8,0,0,0,0,0,0,0,0,0,0,0},
 {0,5,0,-20,0,16,0,0,0,0,0,0,0,0,0,0},
 {-1,0,18,0,-48,0,32,0,0,0,0,0,0,0,0,0},
 {0,-7,0,56,0,-112,0,64,0,0,0,0,0,0,0,0},
 {1,0,-32,0,160,0,-256,0,128,0,0,0,0,0,0,0},
 {0,9,0,-120,0,432,0,-576,0,256,0,0,0,0,0},
 {-1,0,50,0,-400,0,1120,0,-1280,0,512,0,0,0,0,0},
 {0,-11,0,220,0,-1232,0,2816,0,-2816,0,1024,0,0,0,0},
 {1,0,-72,0,840,0,-3584,0,6912,0,-6144,0,2048,0,0,0},
 {0,13,0,-364,0,2912,0,-9984,0,16640,0,-13312,0,4096,0,0},
 {-1,0,98,0,-1568,0,9408,0,-26880,0,39424,0,-28672,0,8192,0},
 {0,-15,0,560,0,-6048,0,28800,0,-70400,0,92160,0,-61440,0,16384}};

// DPP add: x + dpp_move(x). All-VALU cross-lane (no LDS pipe, no lgkmcnt).
template <int C>
__device__ __forceinline__ float dppadd(float x) {
    return x + __builtin_bit_cast(float,
        __builtin_amdgcn_update_dpp(0, __builtin_bit_cast(int, x), C, 0xF, 0xF, true));
}
__device__ __forceinline__ float red_oct(float x) {       // sum over each octet
    x = dppadd<0xB1>(x); x = dppadd<0x4E>(x); x = dppadd<0x141>(x); return x;
}
__device__ __forceinline__ float red_wave64(float x) {    // valid in lane 63
    x = dppadd<0xB1>(x); x = dppadd<0x4E>(x); x = dppadd<0x141>(x);
    x = dppadd<0x140>(x); x = dppadd<0x142>(x); x = dppadd<0x143>(x); return x;
}
__device__ __forceinline__ float red_half32(float x) {    // 32-lane sums
    x = dppadd<0xB1>(x); x = dppadd<0x4E>(x); x = dppadd<0x141>(x);
    x = dppadd<0x140>(x); x = dppadd<0x142>(x); return x;
}

// One block per batch element; 256-step recurrence in-block, ONE barrier/step.
// Attention collapsed (setup) to degree-15 monomial poly.
// Thread role remap (vs earlier rounds): g = 16*wave + (lane&15), redundancy
// index = lane>>4 (also the MFMA k-group and the monomial residue class).
// With B-tile rt covering gate rows 128*rt + 16*wave + [0,16), the MFMA
// C layout (col = lane&15, all rows identical since A = h broadcast) puts
// ALL FOUR gates of this thread's g in acc[rt][0] locally: no bpermute, no
// selects, no LDS staging of gates. Activations computed redundantly (x4).
// h goes straight to global each step (async, vmcnt never drained in-loop);
// the f16 h double-buffer is the only per-step LDS state. Step barrier is
// raw s_barrier + lgkmcnt(0) so the global stores stay in flight.
__global__ __launch_bounds__(NT, 2)
void attn_lstm_decoder(const float* __restrict__ enc,   // [B,S,E]
                       const float* __restrict__ W1w,   // [S,S]
                       const float* __restrict__ W1b,   // [S]
                       const float* __restrict__ W2w,   // [S,2S]
                       const float* __restrict__ W2b,   // [S]
                       const float* __restrict__ Wih,   // [4D,E]
                       const float* __restrict__ Whh,   // [4D,D]
                       const float* __restrict__ bih,   // [4D]
                       const float* __restrict__ bhh,   // [4D]
                       float* __restrict__ out)         // [S,B,D]
{
    const int b    = blockIdx.x;
    const int t    = threadIdx.x;
    const int wave = t >> 6;
    const int lane = t & 63;
    const int grp  = lane >> 4;       // MFMA k-group / residue class / copy idx
    const int nib  = lane & 15;       // MFMA n-index == g within the wave
    const int gl   = 16 * wave + nib; // this thread's decoder dim index
    const bool qb0 = grp & 1;
    const bool qb1 = grp & 2;
    // setup-only:
    const int half = lane >> 5;
    const int idx  = lane & 31;
    const int jnode = 2 * wave + half;

    __shared__ __align__(16) _Float16 hist16[2 * SLOTH]; // f16 h double buffer
    __shared__ __align__(16) float xwbuf[2][16];        // 8 waves x float2 partial x
    __shared__ float A2_l[NS];
    __shared__ float g2_l[NS];
    __shared__ float e0_l[NS];
    __shared__ float e1_l[NS];
    __shared__ float Ml[NN * NN];
    __shared__ float2 Pn[NN];
    __shared__ float2 Vl[NN];
    __shared__ float Pm0[NN], Pm1[NN];

    // ---------------- setup (once per block) ----------------
    {
        float v = enc[b * (NS * NE) + t];      // coalesced
        if (t & 1) e1_l[t >> 1] = v; else e0_l[t >> 1] = v;
    }
    if (t < NN * NN) {
        const int mi = t >> 4, mj = t & 15;
        const float w = (mi == 0) ? (1.0f / NN) : (2.0f / NN);
        Ml[t] = w * __cosf((float)(mi * (2 * mj + 1)) * (PI_F / (2 * NN)));
    }
    __syncthreads();

    // w1sum rows and w2term rows: 32 rows per wave (DPP reductions).
    for (int r = 0; r < 32; ++r) {
        const int s = wave * 32 + r;
        float p = W1w[s * NS + lane]       + W1w[s * NS + lane + 64]
                + W1w[s * NS + lane + 128] + W1w[s * NS + lane + 192];
        p = red_wave64(p);
        if (lane == 63) g2_l[s] = p * (2.0f * L2E);
        float qq = 0.0f;
        #pragma unroll
        for (int kk = 0; kk < 8; ++kk) {
            const int c = lane + kk * 64;
            const float ev = (c & 1) ? e1_l[c >> 1] : e0_l[c >> 1];
            qq = fmaf(ev, W2w[s * (2 * NS) + c], qq);
        }
        qq = red_wave64(qq);
        if (lane == 63) A2_l[s] = (qq + W2b[s] + W1b[s]) * (2.0f * L2E);
    }
    __syncthreads();

    // One-time node softmax: F(y_j) for the 16 Chebyshev nodes (2 nodes/wave).
    {
        const float y  = __cosf((float)(2 * jnode + 1) * (PI_F / (2 * NN)));
        const float C2 = -2.0f * L2E;
        float l = 0.0f, p0 = 0.0f, p1 = 0.0f;
        #pragma unroll
        for (int k = 0; k < 8; ++k) {
            const int s = k * 32 + idx;
            const float m1 = fmaf(y, g2_l[s], A2_l[s]);
            const float u  = __builtin_amdgcn_exp2f(m1);
            const float rc = __builtin_amdgcn_rcpf(u + 1.0f);
            const float e  = __builtin_amdgcn_exp2f(rc * C2);
            l += e;
            p0 = fmaf(e, e0_l[s], p0);
            p1 = fmaf(e, e1_l[s], p1);
        }
        l = red_half32(l); p0 = red_half32(p0); p1 = red_half32(p1);
        if ((lane & 31) == 31) {
            const float rl = __builtin_amdgcn_rcpf(l);
            Pn[jnode] = make_float2(p0 * rl, p1 * rl);
        }
    }
    __syncthreads();

    // DCT collapse: V[i] = sum_j M[i][j]*Pn[j], 1/ND folded in.
    if (t < NN) {
        float v0 = 0.0f, v1 = 0.0f;
        #pragma unroll
        for (int j = 0; j < NN; ++j) {
            v0 = fmaf(Ml[t * NN + j], Pn[j].x, v0);
            v1 = fmaf(Ml[t * NN + j], Pn[j].y, v1);
        }
        Vl[t] = make_float2(v0 * (1.0f / ND), v1 * (1.0f / ND));
    }

    // W_hh MFMA B-fragments, WAVE-LOCAL rows: tile rt (= gate index) covers
    // rows 128*rt + 16*wave + [0,16). Lane holds B[k][n]: n = nib,
    // k = 32*kt + 8*grp + e (contiguous 8, packed little-endian).
    f16x8 wf[4][4];
    #pragma unroll
    for (int rt = 0; rt < 4; ++rt) {
        const int row = 128 * rt + 16 * wave + nib;
        #pragma unroll
        for (int kt = 0; kt < 4; ++kt) {
            const vf4 wa = *reinterpret_cast<const vf4*>(Whh + row * ND + 32 * kt + 8 * grp);
            const vf4 wb = *reinterpret_cast<const vf4*>(Whh + row * ND + 32 * kt + 8 * grp + 4);
            f16x8 wv;
            wv[0] = (_Float16)wa.x; wv[1] = (_Float16)wa.y;
            wv[2] = (_Float16)wa.z; wv[3] = (_Float16)wa.w;
            wv[4] = (_Float16)wb.x; wv[5] = (_Float16)wb.y;
            wv[6] = (_Float16)wb.z; wv[7] = (_Float16)wb.w;
            wf[rt][kt] = wv;
        }
    }
    // All-4-gate per-lane constants for this thread's g (rows 128*j + gl).
    float wi0_[4], wi1_[4], bb_[4];
    #pragma unroll
    for (int j = 0; j < 4; ++j) {
        const int r = 128 * j + gl;
        wi0_[j] = Wih[r * 2 + 0];
        wi1_[j] = Wih[r * 2 + 1];
        bb_[j]  = bih[r] + bhh[r];
    }

    // zero-init h buffer slot 1 (input of step 0)
    if (t < ND) hist16[SLOTH + 40 * (t >> 5) + (t & 31)] = (_Float16)0.0f;
    float h_reg = 0.0f, c_reg = 0.0f;
    __syncthreads();                   // Vl visible

    // Chebyshev -> monomial: Pm[m] = sum_k V[k] * CT[k][m].
    if (t < NN) {
        float s0 = 0.0f, s1 = 0.0f;
        #pragma unroll
        for (int k = 0; k < NN; ++k) {
            s0 = fmaf(Vl[k].x, CT[k][t], s0);
            s1 = fmaf(Vl[k].y, CT[k][t], s1);
        }
        Pm0[t] = s0; Pm1[t] = s1;
    }
    __syncthreads();                   // Pm visible

    // Per-lane residue-class coefficients: G_e(h) = sum_q h^q * Q_q(h^4),
    // residue q = grp for this lane.
    float Q0[4], Q1[4];
    #pragma unroll
    for (int i = 0; i < 4; ++i) { Q0[i] = Pm0[4 * i + grp]; Q1[i] = Pm1[4 * i + grp]; }

    // phaseG: residue-split monomial eval at this lane's own h; the full
    // wave sum over (16 g) x (4 residues) IS the wave's x partial.
    auto phaseG = [&](float h, int pw) {
        const float h2 = h * h;
        const float h3 = h2 * h;
        const float h4 = h2 * h2;
        const float hq = qb1 ? (qb0 ? h3 : h2) : (qb0 ? h : 1.0f);
        float a0 = fmaf(Q0[3], h4, Q0[2]);
        a0 = fmaf(a0, h4, Q0[1]);
        a0 = fmaf(a0, h4, Q0[0]);
        float a1 = fmaf(Q1[3], h4, Q1[2]);
        a1 = fmaf(a1, h4, Q1[1]);
        a1 = fmaf(a1, h4, Q1[0]);
        a0 *= hq;
        a1 *= hq;
        a0 = red_wave64(a0); a1 = red_wave64(a1);  // sum over wave's 16 g
        if (lane == 63) {
            xwbuf[pw][2 * wave + 0] = a0;
            xwbuf[pw][2 * wave + 1] = a1;
        }
    };

    phaseG(0.0f, 0);       // x for step 0 (h = 0)
    __syncthreads();

    const int hoff = 40 * (gl >> 5) + (gl & 31);   // this lane's h slot offset

    // ---------------- the recurrence (ONE barrier per step) ----------------
    for (int step = 0; step < NS; ++step) {
        const int pr = step & 1;
        const int rs = pr ^ 1;            // buffer holding h(step-1)
        const int ws = pr;                // buffer for h(step)

        // A fragments: each 16-lane group reads the SAME 16B of h (broadcast),
        // so A[m][k] = h[k] for every m; all C rows are identical.
        f16x8 af[4];
        const _Float16* hsl = &hist16[rs * SLOTH + 8 * grp];
        #pragma unroll
        for (int kt = 0; kt < 4; ++kt)
            af[kt] = __builtin_bit_cast(f16x8,
                *reinterpret_cast<const int4*>(hsl + 40 * kt));

        // x partials (independent of the A loads / MFMAs)
        float2 xv = *reinterpret_cast<const float2*>(&xwbuf[pr][2 * (lane & 7)]);
        const float x0 = red_oct(xv.x);
        const float x1 = red_oct(xv.y);
        float bt[4];
        #pragma unroll
        for (int j = 0; j < 4; ++j)
            bt[j] = fmaf(x0, wi0_[j], fmaf(x1, wi1_[j], bb_[j]));

        // Gate matvec on the MFMA pipe: 8 independent depth-2 chains.
        float ga[4];
        #pragma unroll
        for (int rt = 0; rt < 4; ++rt) {
            f32x4 a0 = {0.0f, 0.0f, 0.0f, 0.0f};
            f32x4 a1 = {0.0f, 0.0f, 0.0f, 0.0f};
            a0 = __builtin_amdgcn_mfma_f32_16x16x32_f16(af[0], wf[rt][0], a0, 0, 0, 0);
            a1 = __builtin_amdgcn_mfma_f32_16x16x32_f16(af[2], wf[rt][2], a1, 0, 0, 0);
            a0 = __builtin_amdgcn_mfma_f32_16x16x32_f16(af[1], wf[rt][1], a0, 0, 0, 0);
            a1 = __builtin_amdgcn_mfma_f32_16x16x32_f16(af[3], wf[rt][3], a1, 0, 0, 0);
            ga[rt] = a0[0] + a1[0];
        }

        // All four gates are local now: acc[rt][0] is gate rt at column gl.
        const float gi = ga[0] + bt[0];
        const float gf = ga[1] + bt[1];
        const float gg = ga[2] + bt[2];
        const float go = ga[3] + bt[3];

        const float si = __builtin_amdgcn_rcpf(1.0f + __builtin_amdgcn_exp2f(-L2E * gi));
        const float sf = __builtin_amdgcn_rcpf(1.0f + __builtin_amdgcn_exp2f(-L2E * gf));
        const float so = __builtin_amdgcn_rcpf(1.0f + __builtin_amdgcn_exp2f(-L2E * go));
        const float tg = 1.0f - 2.0f * __builtin_amdgcn_rcpf(
            __builtin_amdgcn_exp2f(2.0f * L2E * gg) + 1.0f);
        c_reg = fmaf(sf, c_reg, si * tg);
        const float tc2 = 1.0f - 2.0f * __builtin_amdgcn_rcpf(
            __builtin_amdgcn_exp2f(2.0f * L2E * c_reg) + 1.0f);
        h_reg = so * tc2;

        if (grp == 0) {
            hist16[ws * SLOTH + hoff] = (_Float16)h_reg;
            out[(size_t)step * (NB * ND) + b * ND + gl] = h_reg;  // async store
        }
        phaseG(h_reg, pr ^ 1);                            // x for step k+1

        // LDS-only drain + raw barrier: global stores stay in flight.
        asm volatile("s_waitcnt lgkmcnt(0)" ::: "memory");
        __builtin_amdgcn_s_barrier();
    }
}

extern "C" void kernel_launch(void* const* d_in, const int* in_sizes, int n_in,
                              void* d_out, int out_size, void* d_ws, size_t ws_size,
                              hipStream_t stream) {
    const float* enc = (const float*)d_in[0];
    const float* W1w = (const float*)d_in[1];
    const float* W1b = (const float*)d_in[2];
    const float* W2w = (const float*)d_in[3];
    const float* W2b = (const float*)d_in[4];
    const float* Wih = (const float*)d_in[5];
    const float* Whh = (const float*)d_in[6];
    const float* bih = (const float*)d_in[7];
    const float* bhh = (const float*)d_in[8];
    attn_lstm_decoder<<<NB, NT, 0, stream>>>(enc, W1w, W1b, W2w, W2b,
                                             Wih, Whh, bih, bhh, (float*)d_out);
}